// Round 1
// baseline (9591.136 us; speedup 1.0000x reference)
//
#include <hip/hip_runtime.h>
#include <math.h>

// ---------------- problem constants ----------------
// B=64, P=196, H=E=A=512, V=10000, T=49, gates=2048, Kx=1536

// ---------------- ws layout (element offsets) ----------------
#define WS_SORT   0             // int[64]
#define WS_DL     64            // int[64]
#define WS_NB     128           // int[64]: nb[0..48], [49]=R, [60]=grid barrier
#define WS_ROWOFF 192           // int[64] (50 used)
#define WS_CAPS   256           // int[64*50]
#define WS_RMAP   3456          // int[3136]: t*64+b per compact row
#define WS_H      6592          // float[64*512]
#define WS_C      39360         // float[64*512]
#define WS_ATT2   72128         // float[64*512] (includes b_dec)
#define WS_E      104896        // float[64*200] exp(e) values
#define WS_Z      117696        // float[4][64] expsum partials
#define WS_CTXP   117952        // float[4][64][512] unnormalized ctx partials
#define WS_PG     249024        // float[16][64][2048] gates k-split partials
#define WS_HALL   2346176       // float[3136*512] compact h_new rows
#define WS_ENC    3951808       // float[12544*512] enc_att
#define WS_BAR    (WS_NB + 60)  // int: grid barrier counter (slack in WS_NB)

// ---------------- out layout (floats) ----------------
#define OUT_SCORES 0            // (64,49,10000)
#define OUT_CAPS   31360000     // (64,50)
#define OUT_DL     31363200     // (64,)
#define OUT_W      31363264     // (64,49,196)
#define OUT_SORT   31977920     // (64,)

#define KC  32
#define LST 68

__device__ __forceinline__ float sigm(float x) { return 1.f / (1.f + expf(-x)); }

__device__ __forceinline__ float4 f4add(float4 a, float4 b) {
  return make_float4(a.x + b.x, a.y + b.y, a.z + b.z, a.w + b.w);
}

// ---------------- fp32 GEMM core: 64 threads, 64x64 tile, 8x8 micro ----------------
__device__ __forceinline__ void gemm_acc(const float* __restrict__ As, const float* __restrict__ Bs,
                                         float acc[8][8], int tx, int ty) {
#pragma unroll 8
  for (int kk = 0; kk < KC; ++kk) {
    const float4* ar = (const float4*)(As + kk * LST + tx * 8);
    const float4* br = (const float4*)(Bs + kk * LST + ty * 8);
    float4 a0 = ar[0], a1 = ar[1];
    float4 b0 = br[0], b1 = br[1];
    float av[8] = {a0.x, a0.y, a0.z, a0.w, a1.x, a1.y, a1.z, a1.w};
    float bv[8] = {b0.x, b0.y, b0.z, b0.w, b1.x, b1.y, b1.z, b1.w};
#pragma unroll
    for (int i = 0; i < 8; ++i)
#pragma unroll
      for (int j = 0; j < 8; ++j)
        acc[i][j] = fmaf(av[i], bv[j], acc[i][j]);
  }
}

__device__ __forceinline__ void load_tile_strided(const float* __restrict__ src, int row0, int ld, int k0,
                                                  float* __restrict__ dst, int tid, int nrows_valid) {
#pragma unroll
  for (int i = 0; i < 8; ++i) {
    int lin = tid + 64 * i;
    int m = lin >> 3, kf = lin & 7;
    float4 v = make_float4(0.f, 0.f, 0.f, 0.f);
    if (m < nrows_valid) v = *(const float4*)(src + (long)(row0 + m) * ld + k0 + kf * 4);
    dst[(kf * 4 + 0) * LST + m] = v.x;
    dst[(kf * 4 + 1) * LST + m] = v.y;
    dst[(kf * 4 + 2) * LST + m] = v.z;
    dst[(kf * 4 + 3) * LST + m] = v.w;
  }
}

__device__ __forceinline__ void load_tile_gather(const float* __restrict__ src, const int* __restrict__ bases,
                                                 int k0, float* __restrict__ dst, int tid) {
#pragma unroll
  for (int i = 0; i < 8; ++i) {
    int lin = tid + 64 * i;
    int m = lin >> 3, kf = lin & 7;
    float4 v = *(const float4*)(src + bases[m] + k0 + kf * 4);
    dst[(kf * 4 + 0) * LST + m] = v.x;
    dst[(kf * 4 + 1) * LST + m] = v.y;
    dst[(kf * 4 + 2) * LST + m] = v.z;
    dst[(kf * 4 + 3) * LST + m] = v.w;
  }
}

// ---------------- device-wide barrier (agent scope, cross-XCD safe) ----------------
__device__ __forceinline__ void gsync(int* bar, int target) {
  __syncthreads();
  if (threadIdx.x == 0) {
    __hip_atomic_fetch_add(bar, 1, __ATOMIC_RELEASE, __HIP_MEMORY_SCOPE_AGENT);
    while (__hip_atomic_load(bar, __ATOMIC_RELAXED, __HIP_MEMORY_SCOPE_AGENT) < target)
      __builtin_amdgcn_s_sleep(1);
    __threadfence();   // acquire side: invalidate L1/L2 so remote writes are visible
  }
  __syncthreads();
}

// ---------------- setup ----------------
__global__ __launch_bounds__(64) void setup_kernel(const int* __restrict__ caps, const int* __restrict__ caplens,
                                                   float* __restrict__ ws, float* __restrict__ out) {
  __shared__ int cl_s[64], so_s[64], dl_s[64], nb_s[49], ro_s[50];
  int i = threadIdx.x;
  cl_s[i] = caplens[i];
  __syncthreads();
  int cli = cl_s[i];
  int r = 0;
  for (int j = 0; j < 64; ++j) {
    int clj = cl_s[j];
    r += (clj > cli) || (clj == cli && j < i);   // stable descending
  }
  so_s[r] = i;
  dl_s[r] = cli - 1;
  __syncthreads();
  int* iws = (int*)ws;
  if (i == 0) iws[WS_BAR] = 0;   // reset grid barrier every run (graph replay safe)
  iws[WS_SORT + i] = so_s[i];
  iws[WS_DL + i] = dl_s[i];
  out[OUT_SORT + i] = (float)so_s[i];
  out[OUT_DL + i] = (float)dl_s[i];
  if (i < 49) {
    int n = 0;
    for (int b = 0; b < 64; ++b) n += (dl_s[b] > i);
    iws[WS_NB + i] = n;
    nb_s[i] = n;
  }
  __syncthreads();
  if (i == 0) {
    int acc = 0;
    for (int t = 0; t < 49; ++t) { ro_s[t] = acc; acc += nb_s[t]; }
    ro_s[49] = acc;
    iws[WS_NB + 49] = acc;
  }
  __syncthreads();
  if (i < 50) iws[WS_ROWOFF + i] = ro_s[i];
  int R = ro_s[49];
  for (int rr = i; rr < 3136; rr += 64) {
    int val = 0;
    if (rr < R) {
      int t = 0;
      while (t < 48 && ro_s[t + 1] <= rr) ++t;
      val = t * 64 + (rr - ro_s[t]);
    }
    iws[WS_RMAP + rr] = val;
  }
  for (int j = i; j < 3200; j += 64) {
    int k = j / 50, jj = j - k * 50;
    int cv = caps[so_s[k] * 50 + jj];
    iws[WS_CAPS + j] = cv;
    out[OUT_CAPS + j] = (float)cv;
  }
}

// ---------------- zero scores+weights+h/c, att2 = b_dec ----------------
__global__ void zero_init_kernel(float* __restrict__ out, float* __restrict__ ws, const float* __restrict__ b_dec) {
  const float4 z = make_float4(0.f, 0.f, 0.f, 0.f);
  float4* out4 = (float4*)out;
  float4* ws4 = (float4*)ws;
  const float4* bd4 = (const float4*)b_dec;
  for (long idx = (long)blockIdx.x * 256 + threadIdx.x; idx < 8018240L; idx += (long)gridDim.x * 256) {
    if (idx < 7840000L) {
      out4[idx] = z;                                   // scores
    } else if (idx < 7993664L) {
      out4[7840816L + (idx - 7840000L)] = z;           // weights
    } else if (idx < 8010048L) {
      ws4[1648L + (idx - 7993664L)] = z;               // h, c
    } else {
      long j = idx - 8010048L;
      ws4[18032L + j] = bd4[j & 127];                  // att2 = b_dec
    }
  }
}

// ---------------- enc_att = feats_sorted @ W_enc^T + b_enc ----------------
__global__ __launch_bounds__(64) void encatt_kernel(const float* __restrict__ image, const float* __restrict__ W_enc,
                                                    const float* __restrict__ b_enc, float* __restrict__ ws) {
  __shared__ __align__(16) float As[KC * LST];
  __shared__ __align__(16) float Bs[KC * LST];
  __shared__ int rb[64];
  int tid = threadIdx.x;
  const int* iws = (const int*)ws;
  int mt = blockIdx.x, nt = blockIdx.y;
  {
    int r = mt * 64 + tid;
    int b = r / 196;
    int p = r - b * 196;
    rb[tid] = iws[WS_SORT + b] * 100352 + p * 512;
  }
  float acc[8][8] = {};
  for (int ch = 0; ch < 16; ++ch) {
    __syncthreads();
    load_tile_gather(image, rb, ch * 32, As, tid);
    load_tile_strided(W_enc, nt * 64, 512, ch * 32, Bs, tid, 64);
    __syncthreads();
    gemm_acc(As, Bs, acc, tid & 7, tid >> 3);
  }
  int tx = tid & 7, ty = tid >> 3;
  int r0 = mt * 64 + tx * 8;
  int n0 = nt * 64 + ty * 8;
#pragma unroll
  for (int i = 0; i < 8; ++i) {
    float* cp = ws + WS_ENC + (long)(r0 + i) * 512 + n0;
    *(float4*)(cp)     = make_float4(acc[i][0] + b_enc[n0],     acc[i][1] + b_enc[n0 + 1],
                                     acc[i][2] + b_enc[n0 + 2], acc[i][3] + b_enc[n0 + 3]);
    *(float4*)(cp + 4) = make_float4(acc[i][4] + b_enc[n0 + 4], acc[i][5] + b_enc[n0 + 5],
                                     acc[i][6] + b_enc[n0 + 6], acc[i][7] + b_enc[n0 + 7]);
  }
}

// ---------------- fused 49-step loop: one persistent kernel ----------------
// grid = 256 blocks x 256 threads; 3 device-wide barriers per t
// P1 (64b x 4pg): e=relu(enc+att2)@W_full, exp, Z/ctx partials     [old ectx]
// P2 (512 one-wave 64x64 tiles, wave pairs split K=96): gate partials [old gates]
// P3 (64b x 4as): reduce partials, LSTM, h store, weights, att2(t+1) [old lstm_att2]
__global__ __launch_bounds__(256) void loop_kernel(
    float* __restrict__ ws, const float* __restrict__ image, const float* __restrict__ emb,
    const float* __restrict__ W_ih, const float* __restrict__ W_hh,
    const float* __restrict__ b_ih, const float* __restrict__ b_hh,
    const float* __restrict__ W_dec, const float* __restrict__ b_dec,
    const float* __restrict__ W_full, const float* __restrict__ b_full,
    float* __restrict__ out) {
  // LDS plan (floats): P1: att2_s[512] wf_s[512] e_s[52]
  //                    P2: As[w]=sm+w*1088, Bs[w]=sm+4352+w*1088 (w<4); accred reuses sm[0..8192)
  //                    P3: g[2048] h[512] red[256]
  __shared__ __align__(16) float sm[8704];   // 34.8 KB
  int* bar = ((int*)ws) + WS_BAR;
  const int* iws = (const int*)ws;
  int blk = blockIdx.x;
  int tid = threadIdx.x;
  int syncno = 0;

  for (int t = 0; t < 49; ++t) {
    int nbt = iws[WS_NB + t];

    // ================= P1: ectx =================
    {
      int b = blk >> 2, pg = blk & 3;
      if (b < nbt) {
        float* att2_s = sm;
        float* wf_s = sm + 512;
        float* e_s = sm + 1024;
        for (int a = tid; a < 512; a += 256) {
          att2_s[a] = ws[WS_ATT2 + b * 512 + a];
          wf_s[a] = W_full[a];
        }
        __syncthreads();
        int w = tid >> 6, lane = tid & 63;
        float bf0 = b_full[0];
        for (int idx = w; idx < 49; idx += 4) {
          int p = pg * 49 + idx;
          const float* er = ws + WS_ENC + (long)(b * 196 + p) * 512;
          float acc = 0.f;
#pragma unroll
          for (int a8 = 0; a8 < 8; ++a8) {
            int a = (a8 << 6) + lane;
            float v = er[a] + att2_s[a];
            acc = fmaf(fmaxf(v, 0.f), wf_s[a], acc);
          }
#pragma unroll
          for (int off = 32; off; off >>= 1) acc += __shfl_down(acc, off);
          if (lane == 0) e_s[idx] = expf(acc + bf0);
        }
        __syncthreads();
        if (tid < 49) ws[WS_E + b * 200 + pg * 49 + tid] = e_s[tid];
        if (tid == 0) {
          float zz = 0.f;
          for (int j = 0; j < 49; ++j) zz += e_s[j];
          ws[WS_Z + pg * 64 + b] = zz;
        }
        long sb = (long)iws[WS_SORT + b] * 100352;
        float a0 = 0.f, a1 = 0.f;
        for (int j = 0; j < 49; ++j) {
          float al = e_s[j];
          const float* fp = image + sb + (long)(pg * 49 + j) * 512;
          a0 = fmaf(al, fp[tid], a0);
          a1 = fmaf(al, fp[tid + 256], a1);
        }
        ws[WS_CTXP + pg * 32768 + b * 512 + tid] = a0;
        ws[WS_CTXP + pg * 32768 + b * 512 + 256 + tid] = a1;
      }
    }
    ++syncno; gsync(bar, 256 * syncno);

    // ================= P2: gates partial GEMM =================
    {
      int w = tid >> 6, lane = tid & 63;
      int pairIdx = w >> 1, sub = w & 1;
      int vb = blk * 2 + pairIdx;          // 0..511
      int nt = vb & 31, ks = vb >> 5;      // 32 n-tiles x 16 k-slices (K=96 each)
      float* As_w = sm + w * 1088;
      float* Bs_w = sm + 4352 + w * 1088;
      int tx = lane & 7, ty = lane >> 3;
      float acc[8][8] = {};
      for (int c = 0; c < 3; ++c) {        // wave handles 3 chunks of 16 k
        int k0 = ks * 96 + (sub * 3 + c) * 16;
        // stage A chunk [k0,k0+16) for rows m=0..63
#pragma unroll
        for (int i = 0; i < 4; ++i) {
          int lin = lane + 64 * i;
          int m = lin >> 2, kf = lin & 3;
          float4 v;
          if (k0 < 512) {
            v = *(const float4*)(emb + (long)iws[WS_CAPS + m * 50 + t] * 512 + k0 + kf * 4);
          } else if (k0 < 1024) {
            const float* base = ws + WS_CTXP + m * 512 + (k0 - 512) + kf * 4;
            float4 v0 = *(const float4*)(base);
            float4 v1 = *(const float4*)(base + 32768);
            float4 v2 = *(const float4*)(base + 65536);
            float4 v3 = *(const float4*)(base + 98304);
            float rz = 1.f / (ws[WS_Z + m] + ws[WS_Z + 64 + m] + ws[WS_Z + 128 + m] + ws[WS_Z + 192 + m]);
            v = make_float4((v0.x + v1.x + v2.x + v3.x) * rz, (v0.y + v1.y + v2.y + v3.y) * rz,
                            (v0.z + v1.z + v2.z + v3.z) * rz, (v0.w + v1.w + v2.w + v3.w) * rz);
          } else {
            v = *(const float4*)(ws + WS_H + m * 512 + (k0 - 1024) + kf * 4);
          }
          As_w[(kf * 4 + 0) * 68 + m] = v.x;
          As_w[(kf * 4 + 1) * 68 + m] = v.y;
          As_w[(kf * 4 + 2) * 68 + m] = v.z;
          As_w[(kf * 4 + 3) * 68 + m] = v.w;
        }
        // stage B chunk (weights)
#pragma unroll
        for (int i = 0; i < 4; ++i) {
          int lin = lane + 64 * i;
          int m = lin >> 2, kf = lin & 3;
          const float* src = (k0 < 1024) ? (W_ih + (long)(nt * 64 + m) * 1024 + k0 + kf * 4)
                                         : (W_hh + (long)(nt * 64 + m) * 512 + (k0 - 1024) + kf * 4);
          float4 v = *(const float4*)src;
          Bs_w[(kf * 4 + 0) * 68 + m] = v.x;
          Bs_w[(kf * 4 + 1) * 68 + m] = v.y;
          Bs_w[(kf * 4 + 2) * 68 + m] = v.z;
          Bs_w[(kf * 4 + 3) * 68 + m] = v.w;
        }
        __syncthreads();
#pragma unroll
        for (int kk = 0; kk < 16; ++kk) {
          const float4* ar4 = (const float4*)(As_w + kk * 68 + tx * 8);
          const float4* br4 = (const float4*)(Bs_w + kk * 68 + ty * 8);
          float4 a0v = ar4[0], a1v = ar4[1];
          float4 b0v = br4[0], b1v = br4[1];
          float av[8] = {a0v.x, a0v.y, a0v.z, a0v.w, a1v.x, a1v.y, a1v.z, a1v.w};
          float bv[8] = {b0v.x, b0v.y, b0v.z, b0v.w, b1v.x, b1v.y, b1v.z, b1v.w};
#pragma unroll
          for (int i = 0; i < 8; ++i)
#pragma unroll
            for (int j = 0; j < 8; ++j)
              acc[i][j] = fmaf(av[i], bv[j], acc[i][j]);
        }
        __syncthreads();
      }
      // pair reduce through LDS (reuse As/Bs space: all waves past gemm)
      float* ar = sm + pairIdx * 4096;
      if (sub == 0) {
#pragma unroll
        for (int i = 0; i < 8; ++i) {
          float* dp = ar + (tx * 8 + i) * 64 + ty * 8;
          *(float4*)(dp)     = make_float4(acc[i][0], acc[i][1], acc[i][2], acc[i][3]);
          *(float4*)(dp + 4) = make_float4(acc[i][4], acc[i][5], acc[i][6], acc[i][7]);
        }
      }
      __syncthreads();
      if (sub == 1) {
        float* pgout = ws + WS_PG + ks * 131072;
#pragma unroll
        for (int i = 0; i < 8; ++i) {
          const float* sp = ar + (tx * 8 + i) * 64 + ty * 8;
          float4 r0 = *(const float4*)(sp);
          float4 r1 = *(const float4*)(sp + 4);
          float* cp = pgout + (tx * 8 + i) * 2048 + nt * 64 + ty * 8;
          *(float4*)(cp)     = make_float4(acc[i][0] + r0.x, acc[i][1] + r0.y,
                                           acc[i][2] + r0.z, acc[i][3] + r0.w);
          *(float4*)(cp + 4) = make_float4(acc[i][4] + r1.x, acc[i][5] + r1.y,
                                           acc[i][6] + r1.z, acc[i][7] + r1.w);
        }
      }
    }
    ++syncno; gsync(bar, 256 * syncno);

    // ================= P3: reduce + LSTM + att2(t+1) =================
    {
      int b = blk >> 2, as = blk & 3;
      bool act = (b < nbt);
      float* g = sm;
      float* hsh = sm + 2048;
      float* red = sm + 2560;
      const float4* bi4 = (const float4*)b_ih;
      const float4* bh4 = (const float4*)b_hh;
      const float* pgb = ws + WS_PG + b * 2048;
      int f0 = tid, f1 = tid + 256;
      float4 A0 = f4add(bi4[f0], bh4[f0]);
      float4 A1 = f4add(bi4[f1], bh4[f1]);
#pragma unroll
      for (int ksl = 0; ksl < 16; ++ksl) {
        const float4* p = (const float4*)(pgb + ksl * 131072);
        A0 = f4add(A0, p[f0]);
        A1 = f4add(A1, p[f1]);
      }
      ((float4*)g)[f0] = A0;
      ((float4*)g)[f1] = A1;
      __syncthreads();
      int ro = iws[WS_ROWOFF + t];
#pragma unroll
      for (int r = 0; r < 2; ++r) {
        int hh = tid + r * 256;
        float gi = g[hh], gf = g[512 + hh], gg = g[1024 + hh], go = g[1536 + hh];
        float c = ws[WS_C + b * 512 + hh];
        float cn = sigm(gf) * c + sigm(gi) * tanhf(gg);
        float hn = sigm(go) * tanhf(cn);
        hsh[hh] = hn;
        if (act && as == 0) {
          ws[WS_C + b * 512 + hh] = cn;
          ws[WS_H + b * 512 + hh] = hn;
          ws[WS_HALL + (long)(ro + b) * 512 + hh] = hn;
        }
      }
      if (act && tid < 49) {
        float zz = ws[WS_Z + b] + ws[WS_Z + 64 + b] + ws[WS_Z + 128 + b] + ws[WS_Z + 192 + b];
        int p = as * 49 + tid;
        out[OUT_W + (long)(b * 49 + t) * 196 + p] = ws[WS_E + b * 200 + p] / zz;
      }
      __syncthreads();
      // att2(t+1) for a-range [as*128, as*128+128): 2 threads per a
      int a = as * 128 + (tid >> 1);
      int part = tid & 1;
      const float4* wd = (const float4*)(W_dec + (long)a * 512 + part * 256);
      const float4* hp = (const float4*)(hsh + part * 256);
      float s = 0.f;
#pragma unroll 8
      for (int j = 0; j < 64; ++j) {
        float4 wv = wd[j], hv = hp[j];
        s = fmaf(wv.x, hv.x, s);
        s = fmaf(wv.y, hv.y, s);
        s = fmaf(wv.z, hv.z, s);
        s = fmaf(wv.w, hv.w, s);
      }
      red[tid] = s;
      __syncthreads();
      if (part == 0) ws[WS_ATT2 + b * 512 + a] = red[tid] + red[tid + 1] + b_dec[a];
    }
    if (t < 48) { ++syncno; gsync(bar, 256 * syncno); }
  }
}

// ---------------- post-loop: scores = H_all @ W_score^T + b_score (compact rows) ----------------
__global__ __launch_bounds__(64) void score_kernel(const float* __restrict__ ws, const float* __restrict__ W_score,
                                                   const float* __restrict__ b_score, float* __restrict__ out) {
  __shared__ __align__(16) float As[KC * LST];
  __shared__ __align__(16) float Bs[KC * LST];
  const int* iws = (const int*)ws;
  int mt = blockIdx.x, nt = blockIdx.y;
  int R = iws[WS_NB + 49];
  if (mt * 64 >= R) return;
  int tid = threadIdx.x;
  int mvalid = R - mt * 64; if (mvalid > 64) mvalid = 64;
  int nvalid = 10000 - nt * 64; if (nvalid > 64) nvalid = 64;
  float acc[8][8] = {};
  for (int ch = 0; ch < 16; ++ch) {
    __syncthreads();
    load_tile_strided(ws + WS_HALL, mt * 64, 512, ch * 32, As, tid, mvalid);
    load_tile_strided(W_score, nt * 64, 512, ch * 32, Bs, tid, nvalid);
    __syncthreads();
    gemm_acc(As, Bs, acc, tid & 7, tid >> 3);
  }
  int tx = tid & 7, ty = tid >> 3;
  int n0 = nt * 64 + ty * 8;
#pragma unroll
  for (int i = 0; i < 8; ++i) {
    int r = mt * 64 + tx * 8 + i;
    if (r >= R) continue;
    int tb = iws[WS_RMAP + r];
    int bb = tb & 63, tt = tb >> 6;
    float* cp = out + (long)bb * 490000 + tt * 10000 + n0;
    if (n0 + 4 <= 10000)
      *(float4*)(cp)     = make_float4(acc[i][0] + b_score[n0],     acc[i][1] + b_score[n0 + 1],
                                       acc[i][2] + b_score[n0 + 2], acc[i][3] + b_score[n0 + 3]);
    if (n0 + 8 <= 10000)
      *(float4*)(cp + 4) = make_float4(acc[i][4] + b_score[n0 + 4], acc[i][5] + b_score[n0 + 5],
                                       acc[i][6] + b_score[n0 + 6], acc[i][7] + b_score[n0 + 7]);
  }
}

// ---------------- launch ----------------
extern "C" void kernel_launch(void* const* d_in, const int* in_sizes, int n_in,
                              void* d_out, int out_size, void* d_ws, size_t ws_size,
                              hipStream_t stream) {
  const float* image   = (const float*)d_in[0];
  const int*   caps    = (const int*)d_in[1];
  const int*   caplens = (const int*)d_in[2];
  const float* emb     = (const float*)d_in[3];
  const float* W_ih    = (const float*)d_in[4];
  const float* W_hh    = (const float*)d_in[5];
  const float* b_ih    = (const float*)d_in[6];
  const float* b_hh    = (const float*)d_in[7];
  const float* W_enc   = (const float*)d_in[8];
  const float* b_enc   = (const float*)d_in[9];
  const float* W_dec   = (const float*)d_in[10];
  const float* b_dec   = (const float*)d_in[11];
  const float* W_full  = (const float*)d_in[12];
  const float* b_full  = (const float*)d_in[13];
  const float* W_score = (const float*)d_in[14];
  const float* b_score = (const float*)d_in[15];
  float* out = (float*)d_out;
  float* ws  = (float*)d_ws;

  setup_kernel<<<1, 64, 0, stream>>>(caps, caplens, ws, out);
  zero_init_kernel<<<2048, 256, 0, stream>>>(out, ws, b_dec);
  encatt_kernel<<<dim3(196, 8), 64, 0, stream>>>(image, W_enc, b_enc, ws);
  loop_kernel<<<256, 256, 0, stream>>>(ws, image, emb, W_ih, W_hh, b_ih, b_hh,
                                       W_dec, b_dec, W_full, b_full, out);
  score_kernel<<<dim3(49, 157), 64, 0, stream>>>(ws, W_score, b_score, out);
}

// Round 2
// 5632.859 us; speedup vs baseline: 1.7027x; 1.7027x over previous
//
#include <hip/hip_runtime.h>
#include <math.h>

// ---------------- problem constants ----------------
// B=64, P=196, H=E=A=512, V=10000, T=49, gates=2048, Kx=1536

// ---------------- ws layout (element offsets) ----------------
#define WS_SORT   0             // int[64]
#define WS_DL     64            // int[64]
#define WS_NB     128           // int[64]: nb[0..48], [49]=R
#define WS_ROWOFF 192           // int[64] (50 used)
#define WS_CAPS   256           // int[64*50]
#define WS_RMAP   3456          // int[3136]: t*64+b per compact row
#define WS_H      6592          // float[64*512]
#define WS_C      39360         // float[64*512]
#define WS_CTX    72128         // float[64*512] normalized ctx
#define WS_PG     104896        // float[16][64][2048] gates k-split partials
#define WS_HALL   2202048       // float[3136*512] compact h_new rows
#define WS_ENC    3807680       // float[12544*512] enc_att
// end = 10,230,208 floats = 40.9 MB

// ---------------- out layout (floats) ----------------
#define OUT_SCORES 0            // (64,49,10000)
#define OUT_CAPS   31360000     // (64,50)
#define OUT_DL     31363200     // (64,)
#define OUT_W      31363264     // (64,49,196)
#define OUT_SORT   31977920     // (64,)

#define KC  32
#define LST 68
#define LKW 132                 // 128-tile row stride (128+4)

__device__ __forceinline__ float sigm(float x) { return 1.f / (1.f + expf(-x)); }

__device__ __forceinline__ float4 f4add(float4 a, float4 b) {
  return make_float4(a.x + b.x, a.y + b.y, a.z + b.z, a.w + b.w);
}

// ---------------- 64-tile fp32 GEMM core: 64 threads, 8x8 micro ----------------
__device__ __forceinline__ void gemm_acc(const float* __restrict__ As, const float* __restrict__ Bs,
                                         float acc[8][8], int tx, int ty) {
#pragma unroll 8
  for (int kk = 0; kk < KC; ++kk) {
    const float4* ar = (const float4*)(As + kk * LST + tx * 8);
    const float4* br = (const float4*)(Bs + kk * LST + ty * 8);
    float4 a0 = ar[0], a1 = ar[1];
    float4 b0 = br[0], b1 = br[1];
    float av[8] = {a0.x, a0.y, a0.z, a0.w, a1.x, a1.y, a1.z, a1.w};
    float bv[8] = {b0.x, b0.y, b0.z, b0.w, b1.x, b1.y, b1.z, b1.w};
#pragma unroll
    for (int i = 0; i < 8; ++i)
#pragma unroll
      for (int j = 0; j < 8; ++j)
        acc[i][j] = fmaf(av[i], bv[j], acc[i][j]);
  }
}

__device__ __forceinline__ void load_tile_strided(const float* __restrict__ src, int row0, int ld, int k0,
                                                  float* __restrict__ dst, int tid, int nrows_valid) {
#pragma unroll
  for (int i = 0; i < 8; ++i) {
    int lin = tid + 64 * i;
    int m = lin >> 3, kf = lin & 7;
    float4 v = make_float4(0.f, 0.f, 0.f, 0.f);
    if (m < nrows_valid) v = *(const float4*)(src + (long)(row0 + m) * ld + k0 + kf * 4);
    dst[(kf * 4 + 0) * LST + m] = v.x;
    dst[(kf * 4 + 1) * LST + m] = v.y;
    dst[(kf * 4 + 2) * LST + m] = v.z;
    dst[(kf * 4 + 3) * LST + m] = v.w;
  }
}

__device__ __forceinline__ void load_tile_gather(const float* __restrict__ src, const int* __restrict__ bases,
                                                 int k0, float* __restrict__ dst, int tid) {
#pragma unroll
  for (int i = 0; i < 8; ++i) {
    int lin = tid + 64 * i;
    int m = lin >> 3, kf = lin & 7;
    float4 v = *(const float4*)(src + bases[m] + k0 + kf * 4);
    dst[(kf * 4 + 0) * LST + m] = v.x;
    dst[(kf * 4 + 1) * LST + m] = v.y;
    dst[(kf * 4 + 2) * LST + m] = v.z;
    dst[(kf * 4 + 3) * LST + m] = v.w;
  }
}

// ---------------- 128-tile helpers: 256 threads, KC=16, 8x8 micro (16x16 thread grid) ----------------
__device__ __forceinline__ void stage128_strided(const float* __restrict__ src, int row0, int ld, int k0,
                                                 float* __restrict__ dst, int tid, int nrows_valid) {
#pragma unroll
  for (int i = 0; i < 2; ++i) {
    int lin = tid + 256 * i;          // 0..511
    int m = lin >> 2, kf = lin & 3;   // m 0..127, kf 0..3
    float4 v = make_float4(0.f, 0.f, 0.f, 0.f);
    if (m < nrows_valid) v = *(const float4*)(src + (long)(row0 + m) * ld + k0 + kf * 4);
    dst[(kf * 4 + 0) * LKW + m] = v.x;
    dst[(kf * 4 + 1) * LKW + m] = v.y;
    dst[(kf * 4 + 2) * LKW + m] = v.z;
    dst[(kf * 4 + 3) * LKW + m] = v.w;
  }
}

__device__ __forceinline__ void stage128_gather(const float* __restrict__ src, const int* __restrict__ bases,
                                                int k0, float* __restrict__ dst, int tid) {
#pragma unroll
  for (int i = 0; i < 2; ++i) {
    int lin = tid + 256 * i;
    int m = lin >> 2, kf = lin & 3;
    float4 v = *(const float4*)(src + bases[m] + k0 + kf * 4);
    dst[(kf * 4 + 0) * LKW + m] = v.x;
    dst[(kf * 4 + 1) * LKW + m] = v.y;
    dst[(kf * 4 + 2) * LKW + m] = v.z;
    dst[(kf * 4 + 3) * LKW + m] = v.w;
  }
}

__device__ __forceinline__ void gemm_acc128(const float* __restrict__ As, const float* __restrict__ Bs,
                                            float acc[8][8], int tx, int ty) {
#pragma unroll
  for (int kk = 0; kk < 16; ++kk) {
    const float4* ar = (const float4*)(As + kk * LKW + tx * 8);
    const float4* br = (const float4*)(Bs + kk * LKW + ty * 8);
    float4 a0 = ar[0], a1 = ar[1];
    float4 b0 = br[0], b1 = br[1];
    float av[8] = {a0.x, a0.y, a0.z, a0.w, a1.x, a1.y, a1.z, a1.w};
    float bv[8] = {b0.x, b0.y, b0.z, b0.w, b1.x, b1.y, b1.z, b1.w};
#pragma unroll
    for (int i = 0; i < 8; ++i)
#pragma unroll
      for (int j = 0; j < 8; ++j)
        acc[i][j] = fmaf(av[i], bv[j], acc[i][j]);
  }
}

// ---------------- setup ----------------
__global__ __launch_bounds__(64) void setup_kernel(const int* __restrict__ caps, const int* __restrict__ caplens,
                                                   float* __restrict__ ws, float* __restrict__ out) {
  __shared__ int cl_s[64], so_s[64], dl_s[64], nb_s[49], ro_s[50];
  int i = threadIdx.x;
  cl_s[i] = caplens[i];
  __syncthreads();
  int cli = cl_s[i];
  int r = 0;
  for (int j = 0; j < 64; ++j) {
    int clj = cl_s[j];
    r += (clj > cli) || (clj == cli && j < i);   // stable descending
  }
  so_s[r] = i;
  dl_s[r] = cli - 1;
  __syncthreads();
  int* iws = (int*)ws;
  iws[WS_SORT + i] = so_s[i];
  iws[WS_DL + i] = dl_s[i];
  out[OUT_SORT + i] = (float)so_s[i];
  out[OUT_DL + i] = (float)dl_s[i];
  if (i < 49) {
    int n = 0;
    for (int b = 0; b < 64; ++b) n += (dl_s[b] > i);
    iws[WS_NB + i] = n;
    nb_s[i] = n;
  }
  __syncthreads();
  if (i == 0) {
    int acc = 0;
    for (int t = 0; t < 49; ++t) { ro_s[t] = acc; acc += nb_s[t]; }
    ro_s[49] = acc;
    iws[WS_NB + 49] = acc;
  }
  __syncthreads();
  if (i < 50) iws[WS_ROWOFF + i] = ro_s[i];
  int R = ro_s[49];
  for (int rr = i; rr < 3136; rr += 64) {
    int val = 0;
    if (rr < R) {
      int t = 0;
      while (t < 48 && ro_s[t + 1] <= rr) ++t;
      val = t * 64 + (rr - ro_s[t]);
    }
    iws[WS_RMAP + rr] = val;
  }
  for (int j = i; j < 3200; j += 64) {
    int k = j / 50, jj = j - k * 50;
    int cv = caps[so_s[k] * 50 + jj];
    iws[WS_CAPS + j] = cv;
    out[OUT_CAPS + j] = (float)cv;
  }
}

// ---------------- zero scores+weights+h/c ----------------
__global__ void zero_init_kernel(float* __restrict__ out, float* __restrict__ ws) {
  const float4 z = make_float4(0.f, 0.f, 0.f, 0.f);
  float4* out4 = (float4*)out;
  float4* ws4 = (float4*)ws;
  for (long idx = (long)blockIdx.x * 256 + threadIdx.x; idx < 8010048L; idx += (long)gridDim.x * 256) {
    if (idx < 7840000L) {
      out4[idx] = z;                                   // scores
    } else if (idx < 7993664L) {
      out4[7840816L + (idx - 7840000L)] = z;           // weights
    } else {
      ws4[1648L + (idx - 7993664L)] = z;               // h, c
    }
  }
}

// ---------------- enc_att = feats_sorted @ W_enc^T + b_enc (128-tile) ----------------
__global__ __launch_bounds__(256) void encatt_kernel(const float* __restrict__ image, const float* __restrict__ W_enc,
                                                     const float* __restrict__ b_enc, float* __restrict__ ws) {
  __shared__ __align__(16) float As[16 * LKW];
  __shared__ __align__(16) float Bs[16 * LKW];
  __shared__ int rb[128];
  int tid = threadIdx.x;
  const int* iws = (const int*)ws;
  int mt = blockIdx.x, nt = blockIdx.y;
  if (tid < 128) {
    int r = mt * 128 + tid;
    int b = r / 196;
    int p = r - b * 196;
    rb[tid] = iws[WS_SORT + b] * 100352 + p * 512;
  }
  float acc[8][8] = {};
  for (int ch = 0; ch < 32; ++ch) {
    __syncthreads();
    stage128_gather(image, rb, ch * 16, As, tid);
    stage128_strided(W_enc, nt * 128, 512, ch * 16, Bs, tid, 128);
    __syncthreads();
    gemm_acc128(As, Bs, acc, tid & 15, tid >> 4);
  }
  int tx = tid & 15, ty = tid >> 4;
  int r0 = mt * 128 + tx * 8;
  int n0 = nt * 128 + ty * 8;
#pragma unroll
  for (int i = 0; i < 8; ++i) {
    float* cp = ws + WS_ENC + (long)(r0 + i) * 512 + n0;
    *(float4*)(cp)     = make_float4(acc[i][0] + b_enc[n0],     acc[i][1] + b_enc[n0 + 1],
                                     acc[i][2] + b_enc[n0 + 2], acc[i][3] + b_enc[n0 + 3]);
    *(float4*)(cp + 4) = make_float4(acc[i][4] + b_enc[n0 + 4], acc[i][5] + b_enc[n0 + 5],
                                     acc[i][6] + b_enc[n0 + 6], acc[i][7] + b_enc[n0 + 7]);
  }
}

// ---------------- gates partial GEMM (ctx pre-normalized in WS_CTX) ----------------
__global__ __launch_bounds__(64) void gates_kernel(float* __restrict__ ws, const float* __restrict__ emb,
                                                   const float* __restrict__ W_ih, const float* __restrict__ W_hh,
                                                   int t) {
  __shared__ __align__(16) float As[KC * LST];
  __shared__ __align__(16) float Bs[KC * LST];
  __shared__ int rbe[64];
  int tid = threadIdx.x;
  int nt = blockIdx.x;   // 0..31
  int ks = blockIdx.y;   // 0..15 (96 k's each)
  int* iws = (int*)ws;
  rbe[tid] = iws[WS_CAPS + tid * 50 + t] * 512;
  float acc[8][8] = {};
  for (int ch = 0; ch < 3; ++ch) {
    int k0 = ks * 96 + ch * 32;
    __syncthreads();
    if (k0 < 512) {
      load_tile_gather(emb, rbe, k0, As, tid);
    } else if (k0 < 1024) {
      load_tile_strided(ws + WS_CTX, 0, 512, k0 - 512, As, tid, 64);
    } else {
      load_tile_strided(ws + WS_H, 0, 512, k0 - 1024, As, tid, 64);
    }
    if (k0 < 1024) load_tile_strided(W_ih, nt * 64, 1024, k0, Bs, tid, 64);
    else           load_tile_strided(W_hh, nt * 64, 512, k0 - 1024, Bs, tid, 64);
    __syncthreads();
    gemm_acc(As, Bs, acc, tid & 7, tid >> 3);
  }
  int tx = tid & 7, ty = tid >> 3;
  float* pg = ws + WS_PG + ks * 131072;
  int j0 = nt * 64 + ty * 8;
#pragma unroll
  for (int i = 0; i < 8; ++i) {
    int b = tx * 8 + i;
    float* cp = pg + b * 2048 + j0;
    *(float4*)(cp)     = make_float4(acc[i][0], acc[i][1], acc[i][2], acc[i][3]);
    *(float4*)(cp + 4) = make_float4(acc[i][4], acc[i][5], acc[i][6], acc[i][7]);
  }
}

// ---------------- fused step: [t>=0: reduce PG + LSTM + att2(t+1)] + attention(t+1) ----------------
// grid 64 (one block per sorted batch row) x 256 threads
__global__ __launch_bounds__(256) void step_kernel(float* __restrict__ ws, const float* __restrict__ image,
                                                   const float* __restrict__ b_ih, const float* __restrict__ b_hh,
                                                   const float* __restrict__ W_dec, const float* __restrict__ b_dec,
                                                   const float* __restrict__ W_full, const float* __restrict__ b_full,
                                                   float* __restrict__ out, int t) {
  __shared__ float g[2048];
  __shared__ float h_s[512], att2_s[512], wf_s[512], e_s[200], ctxp_s[2048], zsh[4];
  const int* iws = (const int*)ws;
  int b = blockIdx.x, tid = threadIdx.x;
  int tw = t + 1;

  if (t >= 0) {
    // ---- reduce PG partials -> gates ----
    const float4* bi4 = (const float4*)b_ih;
    const float4* bh4 = (const float4*)b_hh;
    int f0 = tid, f1 = tid + 256;
    float4 A0 = f4add(bi4[f0], bh4[f0]);
    float4 A1 = f4add(bi4[f1], bh4[f1]);
    const float* pgb = ws + WS_PG + b * 2048;
#pragma unroll
    for (int ks = 0; ks < 16; ++ks) {
      const float4* p = (const float4*)(pgb + (long)ks * 131072);
      A0 = f4add(A0, p[f0]);
      A1 = f4add(A1, p[f1]);
    }
    ((float4*)g)[f0] = A0;
    ((float4*)g)[f1] = A1;
    __syncthreads();
    // ---- LSTM cell ----
    bool act = b < iws[WS_NB + t];
    int ro = iws[WS_ROWOFF + t];
#pragma unroll
    for (int r = 0; r < 2; ++r) {
      int hh = tid + 256 * r;
      float gi = g[hh], gf = g[512 + hh], gg = g[1024 + hh], go = g[1536 + hh];
      float c = ws[WS_C + b * 512 + hh];
      float cn = sigm(gf) * c + sigm(gi) * tanhf(gg);
      float hn = sigm(go) * tanhf(cn);
      h_s[hh] = hn;
      if (act) {
        ws[WS_C + b * 512 + hh] = cn;
        ws[WS_H + b * 512 + hh] = hn;
        ws[WS_HALL + (long)(ro + b) * 512 + hh] = hn;
      }
    }
    if (tw > 48 || b >= iws[WS_NB + tw]) return;   // uniform over block
    __syncthreads();
    // ---- att2(t+1) = h_new @ W_dec^T + b_dec (kept in LDS) ----
    const float4* h4 = (const float4*)h_s;
#pragma unroll
    for (int it = 0; it < 2; ++it) {
      int a = it * 256 + tid;
      const float4* wd = (const float4*)(W_dec + (long)a * 512);
      float s = 0.f;
#pragma unroll 16
      for (int j = 0; j < 128; ++j) {
        float4 wv = wd[j], hv = h4[j];
        s = fmaf(wv.x, hv.x, s);
        s = fmaf(wv.y, hv.y, s);
        s = fmaf(wv.z, hv.z, s);
        s = fmaf(wv.w, hv.w, s);
      }
      att2_s[a] = s + b_dec[a];
    }
  } else {
    // prologue: h = 0 -> att2 = b_dec; compute attention(0) for all b
    att2_s[tid] = b_dec[tid];
    att2_s[tid + 256] = b_dec[tid + 256];
  }

  // ---- attention for step tw ----
  for (int a = tid; a < 512; a += 256) wf_s[a] = W_full[a];
  __syncthreads();

  int w = tid >> 6, lane = tid & 63;
  float bf0 = b_full[0];
  for (int idx = w; idx < 196; idx += 4) {
    const float* er = ws + WS_ENC + (long)(b * 196 + idx) * 512;
    float acc = 0.f;
#pragma unroll
    for (int a8 = 0; a8 < 8; ++a8) {
      int a = (a8 << 6) + lane;
      float v = er[a] + att2_s[a];
      acc = fmaf(fmaxf(v, 0.f), wf_s[a], acc);
    }
#pragma unroll
    for (int off = 32; off; off >>= 1) acc += __shfl_down(acc, off);
    if (lane == 0) e_s[idx] = expf(acc + bf0);   // |e| small, no max-sub
  }
  __syncthreads();
  // Z
  float zv = (tid < 196) ? e_s[tid] : 0.f;
#pragma unroll
  for (int off = 32; off; off >>= 1) zv += __shfl_down(zv, off);
  if (lane == 0) zsh[w] = zv;
  __syncthreads();
  float rz = 1.f / (zsh[0] + zsh[1] + zsh[2] + zsh[3]);
  bool wr = (t >= 0) || (b < iws[WS_NB + 0]);
  if (wr && tid < 196) out[OUT_W + (long)(b * 49 + tw) * 196 + tid] = e_s[tid] * rz;
  // ctx: wave w accumulates p in [w*49, w*49+49)
  long sb = (long)iws[WS_SORT + b] * 100352;
  float ac[8] = {};
  for (int j = 0; j < 49; ++j) {
    int p = w * 49 + j;
    float al = e_s[p];
    const float* fp = image + sb + (long)p * 512;
#pragma unroll
    for (int jj = 0; jj < 8; ++jj) ac[jj] = fmaf(al, fp[lane + 64 * jj], ac[jj]);
  }
#pragma unroll
  for (int jj = 0; jj < 8; ++jj) ctxp_s[w * 512 + lane + 64 * jj] = ac[jj];
  __syncthreads();
#pragma unroll
  for (int r = 0; r < 2; ++r) {
    int d = tid + 256 * r;
    ws[WS_CTX + b * 512 + d] =
        (ctxp_s[d] + ctxp_s[512 + d] + ctxp_s[1024 + d] + ctxp_s[1536 + d]) * rz;
  }
}

// ---------------- post-loop: scores = H_all @ W_score^T + b_score (128-tile) ----------------
__global__ __launch_bounds__(256) void score_kernel(const float* __restrict__ ws, const float* __restrict__ W_score,
                                                    const float* __restrict__ b_score, float* __restrict__ out) {
  __shared__ __align__(16) float As[16 * LKW];
  __shared__ __align__(16) float Bs[16 * LKW];
  const int* iws = (const int*)ws;
  int mt = blockIdx.x, nt = blockIdx.y;
  int R = iws[WS_NB + 49];
  if (mt * 128 >= R) return;
  int tid = threadIdx.x;
  int mvalid = R - mt * 128; if (mvalid > 128) mvalid = 128;
  int nvalid = 10000 - nt * 128; if (nvalid > 128) nvalid = 128;
  float acc[8][8] = {};
  for (int ch = 0; ch < 32; ++ch) {
    __syncthreads();
    stage128_strided(ws + WS_HALL, mt * 128, 512, ch * 16, As, tid, mvalid);
    stage128_strided(W_score, nt * 128, 512, ch * 16, Bs, tid, nvalid);
    __syncthreads();
    gemm_acc128(As, Bs, acc, tid & 15, tid >> 4);
  }
  int tx = tid & 15, ty = tid >> 4;
  int n0 = nt * 128 + ty * 8;
#pragma unroll
  for (int i = 0; i < 8; ++i) {
    int r = mt * 128 + tx * 8 + i;
    if (r >= R) continue;
    int tb = iws[WS_RMAP + r];
    int bb = tb & 63, tt = tb >> 6;
    float* cp = out + (long)bb * 490000 + tt * 10000 + n0;
    if (n0 + 4 <= 10000)
      *(float4*)(cp)     = make_float4(acc[i][0] + b_score[n0],     acc[i][1] + b_score[n0 + 1],
                                       acc[i][2] + b_score[n0 + 2], acc[i][3] + b_score[n0 + 3]);
    if (n0 + 8 <= 10000)
      *(float4*)(cp + 4) = make_float4(acc[i][4] + b_score[n0 + 4], acc[i][5] + b_score[n0 + 5],
                                       acc[i][6] + b_score[n0 + 6], acc[i][7] + b_score[n0 + 7]);
  }
}

// ---------------- launch ----------------
extern "C" void kernel_launch(void* const* d_in, const int* in_sizes, int n_in,
                              void* d_out, int out_size, void* d_ws, size_t ws_size,
                              hipStream_t stream) {
  const float* image   = (const float*)d_in[0];
  const int*   caps    = (const int*)d_in[1];
  const int*   caplens = (const int*)d_in[2];
  const float* emb     = (const float*)d_in[3];
  const float* W_ih    = (const float*)d_in[4];
  const float* W_hh    = (const float*)d_in[5];
  const float* b_ih    = (const float*)d_in[6];
  const float* b_hh    = (const float*)d_in[7];
  const float* W_enc   = (const float*)d_in[8];
  const float* b_enc   = (const float*)d_in[9];
  const float* W_dec   = (const float*)d_in[10];
  const float* b_dec   = (const float*)d_in[11];
  const float* W_full  = (const float*)d_in[12];
  const float* b_full  = (const float*)d_in[13];
  const float* W_score = (const float*)d_in[14];
  const float* b_score = (const float*)d_in[15];
  float* out = (float*)d_out;
  float* ws  = (float*)d_ws;

  setup_kernel<<<1, 64, 0, stream>>>(caps, caplens, ws, out);
  zero_init_kernel<<<2048, 256, 0, stream>>>(out, ws);
  encatt_kernel<<<dim3(98, 4), 256, 0, stream>>>(image, W_enc, b_enc, ws);
  // prologue: attention(0) with att2 = b_dec
  step_kernel<<<64, 256, 0, stream>>>(ws, image, b_ih, b_hh, W_dec, b_dec, W_full, b_full, out, -1);
  for (int t = 0; t < 49; ++t) {
    gates_kernel<<<dim3(32, 16), 64, 0, stream>>>(ws, emb, W_ih, W_hh, t);
    step_kernel<<<64, 256, 0, stream>>>(ws, image, b_ih, b_hh, W_dec, b_dec, W_full, b_full, out, t);
  }
  score_kernel<<<dim3(25, 79), 256, 0, stream>>>(ws, W_score, b_score, out);
}

// Round 3
// 2377.520 us; speedup vs baseline: 4.0341x; 2.3692x over previous
//
#include <hip/hip_runtime.h>
#include <math.h>

// ---------------- problem constants ----------------
// B=64, P=196, H=E=A=512, V=10000, T=49, gates=2048, Kx=1536

// ---------------- ws layout (element offsets) ----------------
#define WS_SORT   0             // int[64]
#define WS_DL     64            // int[64]
#define WS_NB     128           // int[64]: nb[0..48], [49]=R
#define WS_ROWOFF 192           // int[64] (50 used)
#define WS_CAPS   256           // int[64*50]
#define WS_RMAP   3456          // int[3136]: t*64+b per compact row
#define WS_H      6592          // float[64*512]
#define WS_C      39360         // float[64*512]
#define WS_ATT2   72128         // float[64*512] (includes b_dec)
#define WS_E      104896        // float[64*200] exp(e) values
#define WS_Z      117696        // float[4][64] expsum partials
#define WS_CTXP   117952        // float[4][64][512] unnormalized ctx partials
#define WS_PG     249024        // float[16][64][2048] gates k-split partials
#define WS_HALL   2346176       // float[3136*512] compact h_new rows
#define WS_ENC    3951808       // float[12544*512] enc_att
// end = 10,374,336 floats = 41.5 MB (proven size)

// ---------------- out layout (floats) ----------------
#define OUT_SCORES 0            // (64,49,10000)
#define OUT_CAPS   31360000     // (64,50)
#define OUT_DL     31363200     // (64,)
#define OUT_W      31363264     // (64,49,196)
#define OUT_SORT   31977920     // (64,)

#define LSW 196                 // swizzled 128-tile row stride (chunks at stride 12)

__device__ __forceinline__ float sigm(float x) { return 1.f / (1.f + expf(-x)); }

__device__ __forceinline__ float4 f4add(float4 a, float4 b) {
  return make_float4(a.x + b.x, a.y + b.y, a.z + b.z, a.w + b.w);
}

// chunk swizzle: logical col m (0..127) -> chunk (m>>3) placed at stride 12
__device__ __forceinline__ int swz128(int m) { return (m >> 3) * 12 + (m & 7); }

// ---------------- 128-tile helpers: 256 threads, KC=16, 8x8 micro ----------------
__device__ __forceinline__ void stage128_strided(const float* __restrict__ src, int row0, int ld, int k0,
                                                 float* __restrict__ dst, int tid, int nrows_valid) {
#pragma unroll
  for (int i = 0; i < 2; ++i) {
    int lin = tid + 256 * i;          // 0..511
    int m = lin >> 2, kf = lin & 3;   // m 0..127, kf 0..3
    float4 v = make_float4(0.f, 0.f, 0.f, 0.f);
    if (m < nrows_valid) v = *(const float4*)(src + (long)(row0 + m) * ld + k0 + kf * 4);
    int mc = swz128(m);
    dst[(kf * 4 + 0) * LSW + mc] = v.x;
    dst[(kf * 4 + 1) * LSW + mc] = v.y;
    dst[(kf * 4 + 2) * LSW + mc] = v.z;
    dst[(kf * 4 + 3) * LSW + mc] = v.w;
  }
}

__device__ __forceinline__ void stage128_gather(const float* __restrict__ src, const int* __restrict__ bases,
                                                int k0, float* __restrict__ dst, int tid) {
#pragma unroll
  for (int i = 0; i < 2; ++i) {
    int lin = tid + 256 * i;
    int m = lin >> 2, kf = lin & 3;
    float4 v = *(const float4*)(src + bases[m] + k0 + kf * 4);
    int mc = swz128(m);
    dst[(kf * 4 + 0) * LSW + mc] = v.x;
    dst[(kf * 4 + 1) * LSW + mc] = v.y;
    dst[(kf * 4 + 2) * LSW + mc] = v.z;
    dst[(kf * 4 + 3) * LSW + mc] = v.w;
  }
}

__device__ __forceinline__ void gemm_acc128(const float* __restrict__ As, const float* __restrict__ Bs,
                                            float acc[8][8], int tx, int ty) {
#pragma unroll
  for (int kk = 0; kk < 16; ++kk) {
    const float4* ar = (const float4*)(As + kk * LSW + tx * 12);
    const float4* br = (const float4*)(Bs + kk * LSW + ty * 12);
    float4 a0 = ar[0], a1 = ar[1];
    float4 b0 = br[0], b1 = br[1];
    float av[8] = {a0.x, a0.y, a0.z, a0.w, a1.x, a1.y, a1.z, a1.w};
    float bv[8] = {b0.x, b0.y, b0.z, b0.w, b1.x, b1.y, b1.z, b1.w};
#pragma unroll
    for (int i = 0; i < 8; ++i)
#pragma unroll
      for (int j = 0; j < 8; ++j)
        acc[i][j] = fmaf(av[i], bv[j], acc[i][j]);
  }
}

// ---------------- setup ----------------
__global__ __launch_bounds__(64) void setup_kernel(const int* __restrict__ caps, const int* __restrict__ caplens,
                                                   float* __restrict__ ws, float* __restrict__ out) {
  __shared__ int cl_s[64], so_s[64], dl_s[64], nb_s[49], ro_s[50];
  int i = threadIdx.x;
  cl_s[i] = caplens[i];
  __syncthreads();
  int cli = cl_s[i];
  int r = 0;
  for (int j = 0; j < 64; ++j) {
    int clj = cl_s[j];
    r += (clj > cli) || (clj == cli && j < i);   // stable descending
  }
  so_s[r] = i;
  dl_s[r] = cli - 1;
  __syncthreads();
  int* iws = (int*)ws;
  iws[WS_SORT + i] = so_s[i];
  iws[WS_DL + i] = dl_s[i];
  out[OUT_SORT + i] = (float)so_s[i];
  out[OUT_DL + i] = (float)dl_s[i];
  if (i < 49) {
    int n = 0;
    for (int b = 0; b < 64; ++b) n += (dl_s[b] > i);
    iws[WS_NB + i] = n;
    nb_s[i] = n;
  }
  __syncthreads();
  if (i == 0) {
    int acc = 0;
    for (int t = 0; t < 49; ++t) { ro_s[t] = acc; acc += nb_s[t]; }
    ro_s[49] = acc;
    iws[WS_NB + 49] = acc;
  }
  __syncthreads();
  if (i < 50) iws[WS_ROWOFF + i] = ro_s[i];
  int R = ro_s[49];
  for (int rr = i; rr < 3136; rr += 64) {
    int val = 0;
    if (rr < R) {
      int t = 0;
      while (t < 48 && ro_s[t + 1] <= rr) ++t;
      val = t * 64 + (rr - ro_s[t]);
    }
    iws[WS_RMAP + rr] = val;
  }
  for (int j = i; j < 3200; j += 64) {
    int k = j / 50, jj = j - k * 50;
    int cv = caps[so_s[k] * 50 + jj];
    iws[WS_CAPS + j] = cv;
    out[OUT_CAPS + j] = (float)cv;
  }
}

// ---------------- zero scores+weights+h/c, att2 = b_dec ----------------
__global__ void zero_init_kernel(float* __restrict__ out, float* __restrict__ ws, const float* __restrict__ b_dec) {
  const float4 z = make_float4(0.f, 0.f, 0.f, 0.f);
  float4* out4 = (float4*)out;
  float4* ws4 = (float4*)ws;
  const float4* bd4 = (const float4*)b_dec;
  for (long idx = (long)blockIdx.x * 256 + threadIdx.x; idx < 8018240L; idx += (long)gridDim.x * 256) {
    if (idx < 7840000L) {
      out4[idx] = z;                                   // scores
    } else if (idx < 7993664L) {
      out4[7840816L + (idx - 7840000L)] = z;           // weights
    } else if (idx < 8010048L) {
      ws4[1648L + (idx - 7993664L)] = z;               // h, c
    } else {
      long j = idx - 8010048L;
      ws4[18032L + j] = bd4[j & 127];                  // att2 = b_dec
    }
  }
}

// ---------------- enc_att = feats_sorted @ W_enc^T + b_enc (128-tile, swizzled LDS) ----------------
__global__ __launch_bounds__(256) void encatt_kernel(const float* __restrict__ image, const float* __restrict__ W_enc,
                                                     const float* __restrict__ b_enc, float* __restrict__ ws) {
  __shared__ __align__(16) float As[16 * LSW];
  __shared__ __align__(16) float Bs[16 * LSW];
  __shared__ int rb[128];
  int tid = threadIdx.x;
  const int* iws = (const int*)ws;
  int mt = blockIdx.x, nt = blockIdx.y;
  if (tid < 128) {
    int r = mt * 128 + tid;
    int b = r / 196;
    int p = r - b * 196;
    rb[tid] = iws[WS_SORT + b] * 100352 + p * 512;
  }
  float acc[8][8] = {};
  for (int ch = 0; ch < 32; ++ch) {
    __syncthreads();
    stage128_gather(image, rb, ch * 16, As, tid);
    stage128_strided(W_enc, nt * 128, 512, ch * 16, Bs, tid, 128);
    __syncthreads();
    gemm_acc128(As, Bs, acc, tid & 15, tid >> 4);
  }
  int tx = tid & 15, ty = tid >> 4;
  int r0 = mt * 128 + tx * 8;
  int n0 = nt * 128 + ty * 8;
#pragma unroll
  for (int i = 0; i < 8; ++i) {
    float* cp = ws + WS_ENC + (long)(r0 + i) * 512 + n0;
    *(float4*)(cp)     = make_float4(acc[i][0] + b_enc[n0],     acc[i][1] + b_enc[n0 + 1],
                                     acc[i][2] + b_enc[n0 + 2], acc[i][3] + b_enc[n0 + 3]);
    *(float4*)(cp + 4) = make_float4(acc[i][4] + b_enc[n0 + 4], acc[i][5] + b_enc[n0 + 5],
                                     acc[i][6] + b_enc[n0 + 6], acc[i][7] + b_enc[n0 + 7]);
  }
}

// ---------------- E: e = relu(enc+att2)@W_full, exp, Z partial, ctx partial ----------------
// grid (64, 4) x 512 threads
__global__ __launch_bounds__(512) void ectx_kernel(float* __restrict__ ws, const float* __restrict__ image,
                                                   const float* __restrict__ W_full, const float* __restrict__ b_full,
                                                   int t) {
  const int* iws = (const int*)ws;
  int b = blockIdx.x;
  if (b >= iws[WS_NB + t]) return;
  int pg = blockIdx.y;
  __shared__ float att2_s[512], wf_s[512], e_s[52];
  int tid = threadIdx.x;
  att2_s[tid] = ws[WS_ATT2 + b * 512 + tid];
  wf_s[tid] = W_full[tid];
  __syncthreads();
  int w = tid >> 6, lane = tid & 63;
  float bf0 = b_full[0];
  for (int idx = w; idx < 49; idx += 8) {
    int p = pg * 49 + idx;
    const float* er = ws + WS_ENC + (long)(b * 196 + p) * 512;
    float acc = 0.f;
#pragma unroll
    for (int a8 = 0; a8 < 8; ++a8) {
      int a = (a8 << 6) + lane;
      float v = er[a] + att2_s[a];
      acc = fmaf(fmaxf(v, 0.f), wf_s[a], acc);
    }
#pragma unroll
    for (int off = 32; off; off >>= 1) acc += __shfl_down(acc, off);
    if (lane == 0) e_s[idx] = expf(acc + bf0);   // |e| small, no max-sub
  }
  __syncthreads();
  if (tid < 49) ws[WS_E + b * 200 + pg * 49 + tid] = e_s[tid];
  if (tid == 0) {
    float zz = 0.f;
    for (int j = 0; j < 49; ++j) zz += e_s[j];
    ws[WS_Z + pg * 64 + b] = zz;
  }
  long sb = (long)iws[WS_SORT + b] * 100352;
  float a0 = 0.f;
  for (int j = 0; j < 49; ++j) {
    a0 = fmaf(e_s[j], image[sb + (long)(pg * 49 + j) * 512 + tid], a0);
  }
  ws[WS_CTXP + pg * 32768 + b * 512 + tid] = a0;
}

// ---------------- G: gates partial GEMM, 4-wave n-split, K=96/block ----------------
// grid (32, 16) x 256 threads; wave w owns n-cols [w*16, w*16+16)
__global__ __launch_bounds__(256) void gates_kernel(float* __restrict__ ws, const float* __restrict__ emb,
                                                    const float* __restrict__ W_ih, const float* __restrict__ W_hh,
                                                    int t) {
  __shared__ __align__(16) float As[96 * 68];
  __shared__ __align__(16) float Bs[96 * 68];
  __shared__ int rbe[64];
  __shared__ float rcpz_s[64];
  int tid = threadIdx.x;
  int nt = blockIdx.x;   // 0..31
  int ks = blockIdx.y;   // 0..15 (96 k's each)
  int* iws = (int*)ws;
  if (tid < 64) {
    rbe[tid] = iws[WS_CAPS + tid * 50 + t] * 512;
    float zz = ws[WS_Z + tid] + ws[WS_Z + 64 + tid] + ws[WS_Z + 128 + tid] + ws[WS_Z + 192 + tid];
    rcpz_s[tid] = 1.f / zz;
  }
  __syncthreads();
  // stage A and B: 3 sub-chunks of 32 k each
#pragma unroll
  for (int c = 0; c < 3; ++c) {
    int k0 = ks * 96 + c * 32;
#pragma unroll
    for (int i = 0; i < 2; ++i) {
      int lin = tid + 256 * i;        // 0..511
      int kf = lin >> 6;              // 0..7
      int m = lin & 63;               // 0..63
      float4 v;
      if (k0 < 512) {
        v = *(const float4*)(emb + (long)rbe[m] + k0 + kf * 4);
      } else if (k0 < 1024) {
        const float* base = ws + WS_CTXP + m * 512 + (k0 - 512) + kf * 4;
        float4 v0 = *(const float4*)(base);
        float4 v1 = *(const float4*)(base + 32768);
        float4 v2 = *(const float4*)(base + 65536);
        float4 v3 = *(const float4*)(base + 98304);
        float rz = rcpz_s[m];
        v = make_float4((v0.x + v1.x + v2.x + v3.x) * rz, (v0.y + v1.y + v2.y + v3.y) * rz,
                        (v0.z + v1.z + v2.z + v3.z) * rz, (v0.w + v1.w + v2.w + v3.w) * rz);
      } else {
        v = *(const float4*)(ws + WS_H + m * 512 + (k0 - 1024) + kf * 4);
      }
      float* da = As + (c * 32 + kf * 4) * 68 + m;
      da[0] = v.x; da[68] = v.y; da[136] = v.z; da[204] = v.w;
      const float* srcB = (k0 < 1024) ? (W_ih + (long)(nt * 64 + m) * 1024 + k0 + kf * 4)
                                      : (W_hh + (long)(nt * 64 + m) * 512 + (k0 - 1024) + kf * 4);
      float4 bv = *(const float4*)srcB;
      float* db = Bs + (c * 32 + kf * 4) * 68 + m;
      db[0] = bv.x; db[68] = bv.y; db[136] = bv.z; db[204] = bv.w;
    }
  }
  __syncthreads();
  int w = tid >> 6, lane = tid & 63;
  int tx = lane & 7, ty = lane >> 3;
  float acc[8][2] = {};
#pragma unroll 8
  for (int kk = 0; kk < 96; ++kk) {
    const float4* ar = (const float4*)(As + kk * 68 + tx * 8);
    float4 a0 = ar[0], a1 = ar[1];
    float2 bv = *(const float2*)(Bs + kk * 68 + w * 16 + ty * 2);
    float av[8] = {a0.x, a0.y, a0.z, a0.w, a1.x, a1.y, a1.z, a1.w};
#pragma unroll
    for (int i = 0; i < 8; ++i) {
      acc[i][0] = fmaf(av[i], bv.x, acc[i][0]);
      acc[i][1] = fmaf(av[i], bv.y, acc[i][1]);
    }
  }
  float* pg = ws + WS_PG + ks * 131072;
  int j0 = nt * 64 + w * 16 + ty * 2;
#pragma unroll
  for (int i = 0; i < 8; ++i) {
    int b = tx * 8 + i;
    *(float2*)(pg + b * 2048 + j0) = make_float2(acc[i][0], acc[i][1]);
  }
}

// ---------------- S: reduce gates, LSTM cell, h_all store, weights out, att2(t+1) ----------------
__global__ __launch_bounds__(512) void lstm_att2_kernel(float* __restrict__ ws, const float* __restrict__ b_ih,
                                                        const float* __restrict__ b_hh, const float* __restrict__ W_dec,
                                                        const float* __restrict__ b_dec, float* __restrict__ out, int t) {
  const int* iws = (const int*)ws;
  int b = blockIdx.x;
  int as = blockIdx.y;          // a-split 0..3
  int hh = threadIdx.x;
  int nb = iws[WS_NB + t];
  __shared__ float h_s[512], red[512];
  float gi = b_ih[hh] + b_hh[hh];
  float gf = b_ih[512 + hh] + b_hh[512 + hh];
  float gg = b_ih[1024 + hh] + b_hh[1024 + hh];
  float go = b_ih[1536 + hh] + b_hh[1536 + hh];
  const float* pgp = ws + WS_PG + b * 2048;
#pragma unroll
  for (int ks = 0; ks < 16; ++ks) {
    const float* p = pgp + ks * 131072;
    gi += p[hh]; gf += p[512 + hh]; gg += p[1024 + hh]; go += p[1536 + hh];
  }
  float c = ws[WS_C + b * 512 + hh];
  float cn = sigm(gf) * c + sigm(gi) * tanhf(gg);
  float hn = sigm(go) * tanhf(cn);
  h_s[hh] = hn;
  if (b < nb) {
    if (as == 0) {
      ws[WS_C + b * 512 + hh] = cn;
      ws[WS_H + b * 512 + hh] = hn;
      ws[WS_HALL + (long)(iws[WS_ROWOFF + t] + b) * 512 + hh] = hn;
    }
    if (hh < 49) {   // weights out for this quarter
      float zz = ws[WS_Z + b] + ws[WS_Z + 64 + b] + ws[WS_Z + 128 + b] + ws[WS_Z + 192 + b];
      int p = as * 49 + hh;
      out[OUT_W + (long)(b * 49 + t) * 196 + p] = ws[WS_E + b * 200 + p] / zz;
    }
  }
  __syncthreads();
  // att2(t+1) for a-range [as*128, as*128+128)
  int a = as * 128 + (hh >> 2);
  int part = hh & 3;
  const float* wd = W_dec + (long)a * 512 + part * 128;
  const float* hp = h_s + part * 128;
  float s = 0.f;
#pragma unroll 8
  for (int j = 0; j < 32; ++j) {
    float4 wv = *(const float4*)(wd + 4 * j);
    s = fmaf(hp[4 * j], wv.x, s);
    s = fmaf(hp[4 * j + 1], wv.y, s);
    s = fmaf(hp[4 * j + 2], wv.z, s);
    s = fmaf(hp[4 * j + 3], wv.w, s);
  }
  red[hh] = s;
  __syncthreads();
  if (part == 0) {
    float v = red[hh] + red[hh + 1] + red[hh + 2] + red[hh + 3] + b_dec[a];
    ws[WS_ATT2 + b * 512 + a] = v;
  }
}

// ---------------- post-loop: scores = H_all @ W_score^T + b_score (128-tile, swizzled LDS) ----------------
__global__ __launch_bounds__(256) void score_kernel(const float* __restrict__ ws, const float* __restrict__ W_score,
                                                    const float* __restrict__ b_score, float* __restrict__ out) {
  __shared__ __align__(16) float As[16 * LSW];
  __shared__ __align__(16) float Bs[16 * LSW];
  const int* iws = (const int*)ws;
  int mt = blockIdx.x, nt = blockIdx.y;
  int R = iws[WS_NB + 49];
  if (mt * 128 >= R) return;
  int tid = threadIdx.x;
  int mvalid = R - mt * 128; if (mvalid > 128) mvalid = 128;
  int nvalid = 10000 - nt * 128; if (nvalid > 128) nvalid = 128;
  float acc[8][8] = {};
  for (int ch = 0; ch < 32; ++ch) {
    __syncthreads();
    stage128_strided(ws + WS_HALL, mt * 128, 512, ch * 16, As, tid, mvalid);
    stage128_strided(W_score, nt * 128, 512, ch * 16, Bs, tid, nvalid);
    __syncthreads();
    gemm_acc128(As, Bs, acc, tid & 15, tid >> 4);
  }
  int tx = tid & 15, ty = tid >> 4;
  int n0 = nt * 128 + ty * 8;
#pragma unroll
  for (int i = 0; i < 8; ++i) {
    int r = mt * 128 + tx * 8 + i;
    if (r >= R) continue;
    int tb = iws[WS_RMAP + r];
    int bb = tb & 63, tt = tb >> 6;
    float* cp = out + (long)bb * 490000 + tt * 10000 + n0;
    if (n0 + 4 <= 10000)
      *(float4*)(cp)     = make_float4(acc[i][0] + b_score[n0],     acc[i][1] + b_score[n0 + 1],
                                       acc[i][2] + b_score[n0 + 2], acc[i][3] + b_score[n0 + 3]);
    if (n0 + 8 <= 10000)
      *(float4*)(cp + 4) = make_float4(acc[i][4] + b_score[n0 + 4], acc[i][5] + b_score[n0 + 5],
                                       acc[i][6] + b_score[n0 + 6], acc[i][7] + b_score[n0 + 7]);
  }
}

// ---------------- launch ----------------
extern "C" void kernel_launch(void* const* d_in, const int* in_sizes, int n_in,
                              void* d_out, int out_size, void* d_ws, size_t ws_size,
                              hipStream_t stream) {
  const float* image   = (const float*)d_in[0];
  const int*   caps    = (const int*)d_in[1];
  const int*   caplens = (const int*)d_in[2];
  const float* emb     = (const float*)d_in[3];
  const float* W_ih    = (const float*)d_in[4];
  const float* W_hh    = (const float*)d_in[5];
  const float* b_ih    = (const float*)d_in[6];
  const float* b_hh    = (const float*)d_in[7];
  const float* W_enc   = (const float*)d_in[8];
  const float* b_enc   = (const float*)d_in[9];
  const float* W_dec   = (const float*)d_in[10];
  const float* b_dec   = (const float*)d_in[11];
  const float* W_full  = (const float*)d_in[12];
  const float* b_full  = (const float*)d_in[13];
  const float* W_score = (const float*)d_in[14];
  const float* b_score = (const float*)d_in[15];
  float* out = (float*)d_out;
  float* ws  = (float*)d_ws;

  setup_kernel<<<1, 64, 0, stream>>>(caps, caplens, ws, out);
  zero_init_kernel<<<2048, 256, 0, stream>>>(out, ws, b_dec);
  encatt_kernel<<<dim3(98, 4), 256, 0, stream>>>(image, W_enc, b_enc, ws);
  for (int t = 0; t < 49; ++t) {
    ectx_kernel<<<dim3(64, 4), 512, 0, stream>>>(ws, image, W_full, b_full, t);
    gates_kernel<<<dim3(32, 16), 256, 0, stream>>>(ws, emb, W_ih, W_hh, t);
    lstm_att2_kernel<<<dim3(64, 4), 512, 0, stream>>>(ws, b_ih, b_hh, W_dec, b_dec, out, t);
  }
  score_kernel<<<dim3(25, 79), 256, 0, stream>>>(ws, W_score, b_score, out);
}